// Round 8
// baseline (356.965 us; speedup 1.0000x reference)
//
#include <hip/hip_runtime.h>
#include <hip/hip_fp16.h>

#define THREADS 256

__device__ __forceinline__ float lrelu(float x) { return x > 0.f ? x : 0.2f * x; }
__device__ __forceinline__ float elu(float x) { return x > 0.f ? x : expm1f(x); }

// ---------------- fused GEMM + alpha (M=128) + fp16 copy ----------------
template <int K, int H, int C>
__global__ __launch_bounds__(256, 6) void gemm_alpha_kernel(
    const float* __restrict__ X, const float* __restrict__ W,
    const float* __restrict__ a_src, const float* __restrict__ a_dst,
    float* __restrict__ Hout, __half* __restrict__ Hh, float* __restrict__ asb,
    float* __restrict__ adb, int nNodes) {
    constexpr int M = 128;
    constexpr int NB = 32;
    __shared__ float xs[NB][K + 1];

    const int t = threadIdx.x;
    const int wid = t >> 6;
    const int lane = t & 63;
    const int half = lane >> 5;
    const int lq = lane & 31;
    const int col4 = lq * 4;
    const int node0 = blockIdx.x * NB;
    const int nbase = node0 + wid * 8 + half * 4;

    for (int i = t; i < NB * K; i += THREADS) {
        int n = i >> 7, k = i & (K - 1);
        int gn = node0 + n;
        xs[n][k] = (gn < nNodes) ? X[(size_t)gn * K + k] : 0.f;
    }
    __syncthreads();

    float acc[4][4];
#pragma unroll
    for (int j = 0; j < 4; ++j)
#pragma unroll
        for (int c = 0; c < 4; ++c) acc[j][c] = 0.f;

    const int nloc = wid * 8 + half * 4;
#pragma unroll 4
    for (int k = 0; k < K; ++k) {
        float4 w4 = *reinterpret_cast<const float4*>(&W[(size_t)k * M + col4]);
        float xv[4];
#pragma unroll
        for (int j = 0; j < 4; ++j) xv[j] = xs[nloc + j][k];
#pragma unroll
        for (int j = 0; j < 4; ++j) {
            acc[j][0] += xv[j] * w4.x;
            acc[j][1] += xv[j] * w4.y;
            acc[j][2] += xv[j] * w4.z;
            acc[j][3] += xv[j] * w4.w;
        }
    }

#pragma unroll
    for (int j = 0; j < 4; ++j) {
        int gn = nbase + j;
        if (gn < nNodes) {
            *reinterpret_cast<float4*>(&Hout[(size_t)gn * M + col4]) =
                make_float4(acc[j][0], acc[j][1], acc[j][2], acc[j][3]);
            __half2 p01 = __floats2half2_rn(acc[j][0], acc[j][1]);
            __half2 p23 = __floats2half2_rn(acc[j][2], acc[j][3]);
            uint2 u = make_uint2(*reinterpret_cast<unsigned*>(&p01),
                                 *reinterpret_cast<unsigned*>(&p23));
            *reinterpret_cast<uint2*>(&Hh[(size_t)gn * M + col4]) = u;
        }
    }

    float as_[4], ad_[4];
#pragma unroll
    for (int c = 0; c < 4; ++c) { as_[c] = a_src[col4 + c]; ad_[c] = a_dst[col4 + c]; }

    float sv[4], dv[4];
#pragma unroll
    for (int j = 0; j < 4; ++j) {
        sv[j] = acc[j][0] * as_[0] + acc[j][1] * as_[1] + acc[j][2] * as_[2] +
                acc[j][3] * as_[3];
        dv[j] = acc[j][0] * ad_[0] + acc[j][1] * ad_[1] + acc[j][2] * ad_[2] +
                acc[j][3] * ad_[3];
    }
#pragma unroll
    for (int off = 1; off < 8; off <<= 1) {
#pragma unroll
        for (int j = 0; j < 4; ++j) {
            sv[j] += __shfl_xor(sv[j], off);
            dv[j] += __shfl_xor(dv[j], off);
        }
    }
    if ((lq & 7) == 0) {
        int h = lq >> 3;
#pragma unroll
        for (int j = 0; j < 4; ++j) {
            int gn = nbase + j;
            if (gn < nNodes) {
                asb[gn * H + h] = sv[j];
                adb[gn * H + h] = dv[j];
            }
        }
    }
}

// ---------------- layer-3 GEMM (M=32) fused alpha + fp16 copy ----------------
template <int K>
__global__ void gemm32_alpha_kernel(const float* __restrict__ X, const float* __restrict__ W,
                                    const float* __restrict__ a_src,
                                    const float* __restrict__ a_dst, float* __restrict__ Hout,
                                    __half* __restrict__ Hh, float* __restrict__ asb,
                                    float* __restrict__ adb, int nNodes) {
    constexpr int M = 32;
    constexpr int NB = 16;
    constexpr int NL = THREADS / M;
    constexpr int PER = NB / NL;
    __shared__ float xs[NB][K];

    int node0 = blockIdx.x * NB;
    for (int i = threadIdx.x; i < NB * K; i += THREADS) {
        int nn = i / K, kk = i % K;
        int n = node0 + nn;
        xs[nn][kk] = (n < nNodes) ? X[(size_t)n * K + kk] : 0.f;
    }
    __syncthreads();

    int col = threadIdx.x & 31;
    int nl = threadIdx.x >> 5;
    float acc[PER];
#pragma unroll
    for (int i = 0; i < PER; ++i) acc[i] = 0.f;

    for (int k = 0; k < K; ++k) {
        float w = W[k * M + col];
#pragma unroll
        for (int i = 0; i < PER; ++i) acc[i] += xs[nl + i * NL][k] * w;
    }

    float as = a_src[col], ad = a_dst[col];
#pragma unroll
    for (int i = 0; i < PER; ++i) {
        int n = node0 + nl + i * NL;
        float sv = acc[i] * as, dv = acc[i] * ad;
#pragma unroll
        for (int off = 1; off < 32; off <<= 1) {
            sv += __shfl_xor(sv, off);
            dv += __shfl_xor(dv, off);
        }
        if (n < nNodes) {
            Hout[(size_t)n * M + col] = acc[i];
            Hh[(size_t)n * M + col] = __float2half(acc[i]);
            if (col == 0) { asb[n] = sv; adb[n] = dv; }
        }
    }
}

// ---------------- CSR build ----------------
__global__ void hist_kernel(const int* __restrict__ dst, int* __restrict__ deg, int nE) {
    int e = blockIdx.x * THREADS + threadIdx.x;
    if (e < nE) atomicAdd(&deg[dst[e]], 1);
}

__global__ void scan1_kernel(const int* __restrict__ deg, int* __restrict__ partial,
                             int* __restrict__ bsum, int n) {
    __shared__ int sh[THREADS];
    int i = blockIdx.x * THREADS + threadIdx.x;
    int v = (i < n) ? deg[i] : 0;
    sh[threadIdx.x] = v;
    __syncthreads();
    for (int off = 1; off < THREADS; off <<= 1) {
        int t = (threadIdx.x >= off) ? sh[threadIdx.x - off] : 0;
        __syncthreads();
        sh[threadIdx.x] += t;
        __syncthreads();
    }
    if (i < n) partial[i] = sh[threadIdx.x];
    if (threadIdx.x == THREADS - 1) bsum[blockIdx.x] = sh[THREADS - 1];
}

__global__ void scan2_kernel(int* __restrict__ bsum, int nblk) {
    __shared__ int sh[THREADS];
    int v = (threadIdx.x < nblk) ? bsum[threadIdx.x] : 0;
    sh[threadIdx.x] = v;
    __syncthreads();
    for (int off = 1; off < THREADS; off <<= 1) {
        int t = (threadIdx.x >= off) ? sh[threadIdx.x - off] : 0;
        __syncthreads();
        sh[threadIdx.x] += t;
        __syncthreads();
    }
    if (threadIdx.x < nblk)
        bsum[threadIdx.x] = (threadIdx.x == 0) ? 0 : sh[threadIdx.x - 1];
}

__global__ void scan3_kernel(const int* __restrict__ partial, const int* __restrict__ bsum,
                             int* __restrict__ rowptr, int* __restrict__ cursor, int n) {
    int i = blockIdx.x * THREADS + threadIdx.x;
    if (i < n) {
        rowptr[i + 1] = partial[i] + bsum[blockIdx.x];
        cursor[i] = 0;
    }
    if (i == 0) rowptr[0] = 0;
}

__global__ void scatter_kernel(const int* __restrict__ src, const int* __restrict__ dst,
                               const int* __restrict__ rowptr, int* __restrict__ cursor,
                               int* __restrict__ csr, int nE) {
    int e = blockIdx.x * THREADS + threadIdx.x;
    if (e >= nE) return;
    int d = dst[e];
    int p = atomicAdd(&cursor[d], 1);
    csr[rowptr[d] + p] = src[e];
}

// ---------------- helper: load H logits for source s ----------------
template <int H>
__device__ __forceinline__ void load_t(const float* __restrict__ asb, int s, bool valid,
                                       const float* adn, float* t) {
    if constexpr (H == 4) {
        float4 a4 = reinterpret_cast<const float4*>(asb)[s];
        float v[4] = {a4.x, a4.y, a4.z, a4.w};
#pragma unroll
        for (int h = 0; h < 4; ++h) t[h] = valid ? lrelu(v[h] + adn[h]) : -3.0e38f;
    } else {
        t[0] = valid ? lrelu(asb[s] + adn[0]) : -3.0e38f;
    }
}

// ---------------- fused per-node softmax + aggregation + ELU ----------------
// Gather geometry: LPE = M/8 lanes per edge (16 B = 8 halfs each),
// EPI = 64/LPE edges per iteration; partial sums combined by shfl_xor.
template <int M, int H, int C>
__global__ void node_aggr(const float* __restrict__ Hf, const __half* __restrict__ Hh,
                          const float* __restrict__ asb, const float* __restrict__ adb,
                          const int* __restrict__ rowptr, const int* __restrict__ csr,
                          const float* __restrict__ bias, float* __restrict__ out,
                          int nNodes) {
    constexpr int LPE = M / 8;   // lanes per edge
    constexpr int EPI = 64 / LPE;  // edges per iteration
    constexpr int WPB = THREADS / 64;
    __shared__ __align__(16) float al_sh[WPB][64 * H];
    __shared__ int off_sh[WPB][64];

    const int wid = threadIdx.x >> 6;
    const int lane = threadIdx.x & 63;
    const int node = blockIdx.x * WPB + wid;
    if (node >= nNodes) return;

    const int g = lane / LPE;    // edge slot within iteration
    const int q = lane % LPE;    // 16B chunk within row
    const int c0 = q * 8;        // first col of this lane's chunk
    const int myh = c0 / C;

    const int e0 = rowptr[node];
    const int deg = rowptr[node + 1] - e0;

    float adn[H], eself[H];
    if constexpr (H == 4) {
        float4 ad4 = reinterpret_cast<const float4*>(adb)[node];
        float4 as4 = reinterpret_cast<const float4*>(asb)[node];
        adn[0] = ad4.x; adn[1] = ad4.y; adn[2] = ad4.z; adn[3] = ad4.w;
        eself[0] = lrelu(as4.x + adn[0]);
        eself[1] = lrelu(as4.y + adn[1]);
        eself[2] = lrelu(as4.z + adn[2]);
        eself[3] = lrelu(as4.w + adn[3]);
    } else {
        adn[0] = adb[node];
        eself[0] = lrelu(asb[node] + adn[0]);
    }

    float m[H], inv[H];
    const bool fast = (deg <= 64);

    if (fast) {
        const bool valid = lane < deg;
        const int s = valid ? csr[e0 + lane] : node;
        float t[H];
        load_t<H>(asb, s, valid, adn, t);
#pragma unroll
        for (int h = 0; h < H; ++h) m[h] = t[h];
#pragma unroll
        for (int off = 32; off > 0; off >>= 1)
#pragma unroll
            for (int h = 0; h < H; ++h) m[h] = fmaxf(m[h], __shfl_xor(m[h], off));
#pragma unroll
        for (int h = 0; h < H; ++h) m[h] = fmaxf(m[h], eself[h]);

        float den[H], ex[H];
#pragma unroll
        for (int h = 0; h < H; ++h) { ex[h] = __expf(t[h] - m[h]); den[h] = ex[h]; }
#pragma unroll
        for (int off = 32; off > 0; off >>= 1)
#pragma unroll
            for (int h = 0; h < H; ++h) den[h] += __shfl_xor(den[h], off);
#pragma unroll
        for (int h = 0; h < H; ++h) {
            den[h] += __expf(eself[h] - m[h]);
            inv[h] = 1.f / (den[h] + 1e-16f);
        }
        if constexpr (H == 4) {
            float4 w = make_float4(ex[0] * inv[0], ex[1] * inv[1], ex[2] * inv[2],
                                   ex[3] * inv[3]);
            *reinterpret_cast<float4*>(&al_sh[wid][lane * 4]) = w;
        } else {
            al_sh[wid][lane] = ex[0] * inv[0];
        }
        off_sh[wid][lane] = s * M;
    } else {
#pragma unroll
        for (int h = 0; h < H; ++h) m[h] = eself[h];
        for (int base = 0; base < deg; base += 64) {
            bool valid = base + lane < deg;
            int s = valid ? csr[e0 + base + lane] : node;
            float t[H];
            load_t<H>(asb, s, valid, adn, t);
#pragma unroll
            for (int h = 0; h < H; ++h) m[h] = fmaxf(m[h], t[h]);
        }
#pragma unroll
        for (int off = 32; off > 0; off >>= 1)
#pragma unroll
            for (int h = 0; h < H; ++h) m[h] = fmaxf(m[h], __shfl_xor(m[h], off));

        float den[H];
#pragma unroll
        for (int h = 0; h < H; ++h) den[h] = 0.f;
        for (int base = 0; base < deg; base += 64) {
            bool valid = base + lane < deg;
            int s = valid ? csr[e0 + base + lane] : node;
            float t[H];
            load_t<H>(asb, s, valid, adn, t);
#pragma unroll
            for (int h = 0; h < H; ++h) den[h] += __expf(t[h] - m[h]);
        }
#pragma unroll
        for (int off = 32; off > 0; off >>= 1)
#pragma unroll
            for (int h = 0; h < H; ++h) den[h] += __shfl_xor(den[h], off);
#pragma unroll
        for (int h = 0; h < H; ++h) {
            den[h] += __expf(eself[h] - m[h]);
            inv[h] = 1.f / (den[h] + 1e-16f);
        }
    }

    // per-lane head scalars
    float mm = m[0], ii = inv[0], es = eself[0];
#pragma unroll
    for (int h = 1; h < H; ++h)
        if (myh == h) { mm = m[h]; ii = inv[h]; es = eself[h]; }

    // ---- gather-accumulate: EPI edges per iteration, 16 B per lane ----
    float acc[8];
#pragma unroll
    for (int c = 0; c < 8; ++c) acc[c] = 0.f;

    auto serial = [&](int cnt) {
        for (int j0 = 0; j0 < cnt; j0 += 2 * EPI) {
#pragma unroll
            for (int u = 0; u < 2; ++u) {
                int j = j0 + u * EPI + g;
                int wo = off_sh[wid][j];
                float al = al_sh[wid][j * H + myh];
                uint4 uv = *reinterpret_cast<const uint4*>(&Hh[wo + c0]);
                float2 f0 = __half22float2(*reinterpret_cast<__half2*>(&uv.x));
                float2 f1 = __half22float2(*reinterpret_cast<__half2*>(&uv.y));
                float2 f2 = __half22float2(*reinterpret_cast<__half2*>(&uv.z));
                float2 f3 = __half22float2(*reinterpret_cast<__half2*>(&uv.w));
                acc[0] += al * f0.x; acc[1] += al * f0.y;
                acc[2] += al * f1.x; acc[3] += al * f1.y;
                acc[4] += al * f2.x; acc[5] += al * f2.y;
                acc[6] += al * f3.x; acc[7] += al * f3.y;
            }
        }
    };

    constexpr int RND = 2 * EPI;
    if (fast) {
        serial((deg + RND - 1) & ~(RND - 1));
    } else {
        for (int base = 0; base < deg; base += 64) {
            bool valid = base + lane < deg;
            int s = valid ? csr[e0 + base + lane] : node;
            float t[H];
            load_t<H>(asb, s, valid, adn, t);
            if constexpr (H == 4) {
                float4 w = make_float4(__expf(t[0] - m[0]) * inv[0],
                                       __expf(t[1] - m[1]) * inv[1],
                                       __expf(t[2] - m[2]) * inv[2],
                                       __expf(t[3] - m[3]) * inv[3]);
                *reinterpret_cast<float4*>(&al_sh[wid][lane * 4]) = w;
            } else {
                al_sh[wid][lane] = __expf(t[0] - m[0]) * inv[0];
            }
            off_sh[wid][lane] = s * M;
            int cl = deg - base;
            if (cl > 64) cl = 64;
            serial((cl + RND - 1) & ~(RND - 1));
        }
    }

    // combine group partials
#pragma unroll
    for (int off = LPE; off < 64; off <<= 1)
#pragma unroll
        for (int c = 0; c < 8; ++c) acc[c] += __shfl_xor(acc[c], off);

    // writer lanes: add self + bias, ELU, store
    if (lane < LPE) {
        const float alSelf = __expf(es - mm) * ii;
        const float* sp = Hf + (size_t)node * M + lane * 8;
        float4 s0 = *reinterpret_cast<const float4*>(sp);
        float4 s1 = *reinterpret_cast<const float4*>(sp + 4);
        const float* bp = bias + lane * 8;
        float4 b0 = *reinterpret_cast<const float4*>(bp);
        float4 b1 = *reinterpret_cast<const float4*>(bp + 4);
        float4 o0 = make_float4(elu(acc[0] + alSelf * s0.x + b0.x),
                                elu(acc[1] + alSelf * s0.y + b0.y),
                                elu(acc[2] + alSelf * s0.z + b0.z),
                                elu(acc[3] + alSelf * s0.w + b0.w));
        float4 o1 = make_float4(elu(acc[4] + alSelf * s1.x + b1.x),
                                elu(acc[5] + alSelf * s1.y + b1.y),
                                elu(acc[6] + alSelf * s1.z + b1.z),
                                elu(acc[7] + alSelf * s1.w + b1.w));
        float* op = out + (size_t)node * M + lane * 8;
        *reinterpret_cast<float4*>(op) = o0;
        *reinterpret_cast<float4*>(op + 4) = o1;
    }
}

// ---------------- mean pool (sorted batch -> segmented reduction) ----------------
__global__ void group_bounds(const int* __restrict__ batch, int* __restrict__ gstart, int N,
                             int G) {
    int g = blockIdx.x * THREADS + threadIdx.x;
    if (g > G) return;
    int lo = 0, hi = N;
    while (lo < hi) {
        int mid = (lo + hi) >> 1;
        if (batch[mid] < g) lo = mid + 1;
        else hi = mid;
    }
    gstart[g] = lo;
}

__global__ void pool_kernel(const float* __restrict__ act, const int* __restrict__ gstart,
                            float* __restrict__ out, int G) {
    int wid = threadIdx.x >> 6;
    int lane = threadIdx.x & 63;
    int g = blockIdx.x * (THREADS / 64) + wid;
    if (g >= G) return;
    int s = gstart[g], e = gstart[g + 1];
    int c = lane & 31, half = lane >> 5;
    float acc = 0.f;
    for (int n = s + half; n < e; n += 2) acc += act[(size_t)n * 32 + c];
    acc += __shfl_xor(acc, 32);
    if (lane < 32) out[g * 32 + c] = acc / fmaxf((float)(e - s), 1.f);
}

extern "C" void kernel_launch(void* const* d_in, const int* in_sizes, int n_in, void* d_out,
                              int out_size, void* d_ws, size_t ws_size, hipStream_t stream) {
    const float* x = (const float*)d_in[0];
    const int* ei = (const int*)d_in[1];
    const int* batch = (const int*)d_in[2];
    const float* W1 = (const float*)d_in[3];
    const float* as1 = (const float*)d_in[4];
    const float* ad1 = (const float*)d_in[5];
    const float* b1 = (const float*)d_in[6];
    const float* W2 = (const float*)d_in[7];
    const float* as2 = (const float*)d_in[8];
    const float* ad2 = (const float*)d_in[9];
    const float* b2 = (const float*)d_in[10];
    const float* W3 = (const float*)d_in[11];
    const float* as3 = (const float*)d_in[12];
    const float* ad3 = (const float*)d_in[13];
    const float* b3 = (const float*)d_in[14];

    const int N = in_sizes[0] / 128;
    const int E = in_sizes[1] / 2;
    const int G = out_size / 32;
    const int* srcp = ei;
    const int* dstp = ei + E;

    char* ws = (char*)d_ws;
    float* A = (float*)ws;                        // N*128 f32
    float* B = A + (size_t)N * 128;               // N*128 f32
    __half* Hh = (__half*)(B + (size_t)N * 128);  // N*128 f16
    float* asb = (float*)(Hh + (size_t)N * 128);  // N*4
    float* adb = asb + (size_t)N * 4;             // N*4
    int* gstart = (int*)(adb + (size_t)N * 4);    // G+1
    int* rowptr = gstart + (G + 1);               // N+1
    int* deg = rowptr + (N + 1);                  // N
    int* cursor = deg + N;                        // N
    int* partial = cursor + N;                    // N
    int* bsum = partial + N;                      // THREADS
    int* csr = bsum + THREADS;                    // E

    const int nblk = (N + THREADS - 1) / THREADS;

    hipMemsetAsync(deg, 0, (size_t)N * 4, stream);

    hist_kernel<<<(E + THREADS - 1) / THREADS, THREADS, 0, stream>>>(dstp, deg, E);
    scan1_kernel<<<nblk, THREADS, 0, stream>>>(deg, partial, bsum, N);
    scan2_kernel<<<1, THREADS, 0, stream>>>(bsum, nblk);
    scan3_kernel<<<nblk, THREADS, 0, stream>>>(partial, bsum, rowptr, cursor, N);
    scatter_kernel<<<(E + THREADS - 1) / THREADS, THREADS, 0, stream>>>(srcp, dstp, rowptr,
                                                                        cursor, csr, E);
    group_bounds<<<(G + 1 + THREADS - 1) / THREADS, THREADS, 0, stream>>>(batch, gstart, N, G);

    const int gaBlocks = (N + 31) / 32;

    // Layer 1: x -> B
    gemm_alpha_kernel<128, 4, 32><<<gaBlocks, THREADS, 0, stream>>>(x, W1, as1, ad1, A, Hh,
                                                                    asb, adb, N);
    node_aggr<128, 4, 32><<<(N + 3) / 4, THREADS, 0, stream>>>(A, Hh, asb, adb, rowptr, csr,
                                                               b1, B, N);
    // Layer 2: B -> B
    gemm_alpha_kernel<128, 4, 32><<<gaBlocks, THREADS, 0, stream>>>(B, W2, as2, ad2, A, Hh,
                                                                    asb, adb, N);
    node_aggr<128, 4, 32><<<(N + 3) / 4, THREADS, 0, stream>>>(A, Hh, asb, adb, rowptr, csr,
                                                               b2, B, N);
    // Layer 3: B -> B (M=32)
    gemm32_alpha_kernel<128><<<(N + 15) / 16, THREADS, 0, stream>>>(B, W3, as3, ad3, A, Hh,
                                                                    asb, adb, N);
    node_aggr<32, 1, 32><<<(N + 3) / 4, THREADS, 0, stream>>>(A, Hh, asb, adb, rowptr, csr,
                                                              b3, B, N);

    pool_kernel<<<(G + 3) / 4, THREADS, 0, stream>>>(B, gstart, (float*)d_out, G);
}

// Round 9
// 331.869 us; speedup vs baseline: 1.0756x; 1.0756x over previous
//
#include <hip/hip_runtime.h>
#include <hip/hip_fp16.h>

#define THREADS 256

__device__ __forceinline__ float lrelu(float x) { return x > 0.f ? x : 0.2f * x; }
__device__ __forceinline__ float elu(float x) { return x > 0.f ? x : expm1f(x); }

// ---------------- fused GEMM + alpha (M=128), fp16 output only ----------------
template <int K, int H, int C>
__global__ __launch_bounds__(256, 6) void gemm_alpha_kernel(
    const float* __restrict__ X, const float* __restrict__ W,
    const float* __restrict__ a_src, const float* __restrict__ a_dst,
    __half* __restrict__ Hh, float* __restrict__ asb, float* __restrict__ adb, int nNodes) {
    constexpr int M = 128;
    constexpr int NB = 32;
    __shared__ float xs[NB][K + 1];

    const int t = threadIdx.x;
    const int wid = t >> 6;
    const int lane = t & 63;
    const int half = lane >> 5;
    const int lq = lane & 31;
    const int col4 = lq * 4;
    const int node0 = blockIdx.x * NB;
    const int nbase = node0 + wid * 8 + half * 4;

    for (int i = t; i < NB * K; i += THREADS) {
        int n = i >> 7, k = i & (K - 1);
        int gn = node0 + n;
        xs[n][k] = (gn < nNodes) ? X[(size_t)gn * K + k] : 0.f;
    }
    __syncthreads();

    float acc[4][4];
#pragma unroll
    for (int j = 0; j < 4; ++j)
#pragma unroll
        for (int c = 0; c < 4; ++c) acc[j][c] = 0.f;

    const int nloc = wid * 8 + half * 4;
#pragma unroll 4
    for (int k = 0; k < K; ++k) {
        float4 w4 = *reinterpret_cast<const float4*>(&W[(size_t)k * M + col4]);
        float xv[4];
#pragma unroll
        for (int j = 0; j < 4; ++j) xv[j] = xs[nloc + j][k];
#pragma unroll
        for (int j = 0; j < 4; ++j) {
            acc[j][0] += xv[j] * w4.x;
            acc[j][1] += xv[j] * w4.y;
            acc[j][2] += xv[j] * w4.z;
            acc[j][3] += xv[j] * w4.w;
        }
    }

#pragma unroll
    for (int j = 0; j < 4; ++j) {
        int gn = nbase + j;
        if (gn < nNodes) {
            __half2 p01 = __floats2half2_rn(acc[j][0], acc[j][1]);
            __half2 p23 = __floats2half2_rn(acc[j][2], acc[j][3]);
            uint2 u = make_uint2(*reinterpret_cast<unsigned*>(&p01),
                                 *reinterpret_cast<unsigned*>(&p23));
            *reinterpret_cast<uint2*>(&Hh[(size_t)gn * M + col4]) = u;
        }
    }

    float as_[4], ad_[4];
#pragma unroll
    for (int c = 0; c < 4; ++c) { as_[c] = a_src[col4 + c]; ad_[c] = a_dst[col4 + c]; }

    float sv[4], dv[4];
#pragma unroll
    for (int j = 0; j < 4; ++j) {
        sv[j] = acc[j][0] * as_[0] + acc[j][1] * as_[1] + acc[j][2] * as_[2] +
                acc[j][3] * as_[3];
        dv[j] = acc[j][0] * ad_[0] + acc[j][1] * ad_[1] + acc[j][2] * ad_[2] +
                acc[j][3] * ad_[3];
    }
#pragma unroll
    for (int off = 1; off < 8; off <<= 1) {
#pragma unroll
        for (int j = 0; j < 4; ++j) {
            sv[j] += __shfl_xor(sv[j], off);
            dv[j] += __shfl_xor(dv[j], off);
        }
    }
    if ((lq & 7) == 0) {
        int h = lq >> 3;
#pragma unroll
        for (int j = 0; j < 4; ++j) {
            int gn = nbase + j;
            if (gn < nNodes) {
                asb[gn * H + h] = sv[j];
                adb[gn * H + h] = dv[j];
            }
        }
    }
}

// ---------------- layer-3 GEMM (M=32) fused alpha, fp16 output only ----------------
template <int K>
__global__ void gemm32_alpha_kernel(const float* __restrict__ X, const float* __restrict__ W,
                                    const float* __restrict__ a_src,
                                    const float* __restrict__ a_dst,
                                    __half* __restrict__ Hh, float* __restrict__ asb,
                                    float* __restrict__ adb, int nNodes) {
    constexpr int M = 32;
    constexpr int NB = 16;
    constexpr int NL = THREADS / M;
    constexpr int PER = NB / NL;
    __shared__ float xs[NB][K];

    int node0 = blockIdx.x * NB;
    for (int i = threadIdx.x; i < NB * K; i += THREADS) {
        int nn = i / K, kk = i % K;
        int n = node0 + nn;
        xs[nn][kk] = (n < nNodes) ? X[(size_t)n * K + kk] : 0.f;
    }
    __syncthreads();

    int col = threadIdx.x & 31;
    int nl = threadIdx.x >> 5;
    float acc[PER];
#pragma unroll
    for (int i = 0; i < PER; ++i) acc[i] = 0.f;

    for (int k = 0; k < K; ++k) {
        float w = W[k * M + col];
#pragma unroll
        for (int i = 0; i < PER; ++i) acc[i] += xs[nl + i * NL][k] * w;
    }

    float as = a_src[col], ad = a_dst[col];
#pragma unroll
    for (int i = 0; i < PER; ++i) {
        int n = node0 + nl + i * NL;
        float sv = acc[i] * as, dv = acc[i] * ad;
#pragma unroll
        for (int off = 1; off < 32; off <<= 1) {
            sv += __shfl_xor(sv, off);
            dv += __shfl_xor(dv, off);
        }
        if (n < nNodes) {
            Hh[(size_t)n * M + col] = __float2half(acc[i]);
            if (col == 0) { asb[n] = sv; adb[n] = dv; }
        }
    }
}

// ---------------- CSR build ----------------
__global__ void hist_kernel(const int* __restrict__ dst, int* __restrict__ deg, int nE) {
    int e = blockIdx.x * THREADS + threadIdx.x;
    if (e < nE) atomicAdd(&deg[dst[e]], 1);
}

__global__ void scan1_kernel(const int* __restrict__ deg, int* __restrict__ partial,
                             int* __restrict__ bsum, int n) {
    __shared__ int sh[THREADS];
    int i = blockIdx.x * THREADS + threadIdx.x;
    int v = (i < n) ? deg[i] : 0;
    sh[threadIdx.x] = v;
    __syncthreads();
    for (int off = 1; off < THREADS; off <<= 1) {
        int t = (threadIdx.x >= off) ? sh[threadIdx.x - off] : 0;
        __syncthreads();
        sh[threadIdx.x] += t;
        __syncthreads();
    }
    if (i < n) partial[i] = sh[threadIdx.x];
    if (threadIdx.x == THREADS - 1) bsum[blockIdx.x] = sh[THREADS - 1];
}

__global__ void scan2_kernel(int* __restrict__ bsum, int nblk) {
    __shared__ int sh[THREADS];
    int v = (threadIdx.x < nblk) ? bsum[threadIdx.x] : 0;
    sh[threadIdx.x] = v;
    __syncthreads();
    for (int off = 1; off < THREADS; off <<= 1) {
        int t = (threadIdx.x >= off) ? sh[threadIdx.x - off] : 0;
        __syncthreads();
        sh[threadIdx.x] += t;
        __syncthreads();
    }
    if (threadIdx.x < nblk)
        bsum[threadIdx.x] = (threadIdx.x == 0) ? 0 : sh[threadIdx.x - 1];
}

__global__ void scan3_kernel(const int* __restrict__ partial, const int* __restrict__ bsum,
                             int* __restrict__ rowptr, int* __restrict__ cursor, int n) {
    int i = blockIdx.x * THREADS + threadIdx.x;
    if (i < n) {
        rowptr[i + 1] = partial[i] + bsum[blockIdx.x];
        cursor[i] = 0;
    }
    if (i == 0) rowptr[0] = 0;
}

__global__ void scatter_kernel(const int* __restrict__ src, const int* __restrict__ dst,
                               const int* __restrict__ rowptr, int* __restrict__ cursor,
                               int* __restrict__ csr, int nE) {
    int e = blockIdx.x * THREADS + threadIdx.x;
    if (e >= nE) return;
    int d = dst[e];
    int p = atomicAdd(&cursor[d], 1);
    csr[rowptr[d] + p] = src[e];
}

// ---------------- helper: load H logits for source s ----------------
template <int H>
__device__ __forceinline__ void load_t(const float* __restrict__ asb, int s, bool valid,
                                       const float* adn, float* t) {
    if constexpr (H == 4) {
        float4 a4 = reinterpret_cast<const float4*>(asb)[s];
        float v[4] = {a4.x, a4.y, a4.z, a4.w};
#pragma unroll
        for (int h = 0; h < 4; ++h) t[h] = valid ? lrelu(v[h] + adn[h]) : -3.0e38f;
    } else {
        t[0] = valid ? lrelu(asb[s] + adn[0]) : -3.0e38f;
    }
}

// ---------------- fused per-node softmax + aggregation + ELU ----------------
// round-7 geometry (CPL channels/lane, 1 edge per unrolled slot, x8 in flight);
// all H reads from fp16 Hh (incl. self row); fp32 accumulate; fp32 out.
template <int M, int H, int C>
__global__ void node_aggr(const __half* __restrict__ Hh, const float* __restrict__ asb,
                          const float* __restrict__ adb, const int* __restrict__ rowptr,
                          const int* __restrict__ csr, const float* __restrict__ bias,
                          float* __restrict__ out, int nNodes) {
    constexpr int CPL = (M + 63) / 64;
    constexpr int WPB = THREADS / 64;
    __shared__ __align__(16) float al_sh[WPB][64 * H];
    __shared__ int off_sh[WPB][64];

    const int wid = threadIdx.x >> 6;
    const int lane = threadIdx.x & 63;
    const int node = blockIdx.x * WPB + wid;
    if (node >= nNodes) return;

    const int e0 = rowptr[node];
    const int deg = rowptr[node + 1] - e0;

    float adn[H], eself[H];
    if constexpr (H == 4) {
        float4 ad4 = reinterpret_cast<const float4*>(adb)[node];
        float4 as4 = reinterpret_cast<const float4*>(asb)[node];
        adn[0] = ad4.x; adn[1] = ad4.y; adn[2] = ad4.z; adn[3] = ad4.w;
        eself[0] = lrelu(as4.x + adn[0]);
        eself[1] = lrelu(as4.y + adn[1]);
        eself[2] = lrelu(as4.z + adn[2]);
        eself[3] = lrelu(as4.w + adn[3]);
    } else {
        adn[0] = adb[node];
        eself[0] = lrelu(asb[node] + adn[0]);
    }

    float m[H], inv[H];
    const bool fast = (deg <= 64);

    if (fast) {
        const bool valid = lane < deg;
        const int s = valid ? csr[e0 + lane] : node;
        float t[H];
        load_t<H>(asb, s, valid, adn, t);
#pragma unroll
        for (int h = 0; h < H; ++h) m[h] = t[h];
#pragma unroll
        for (int off = 32; off > 0; off >>= 1)
#pragma unroll
            for (int h = 0; h < H; ++h) m[h] = fmaxf(m[h], __shfl_xor(m[h], off));
#pragma unroll
        for (int h = 0; h < H; ++h) m[h] = fmaxf(m[h], eself[h]);

        float den[H], ex[H];
#pragma unroll
        for (int h = 0; h < H; ++h) { ex[h] = __expf(t[h] - m[h]); den[h] = ex[h]; }
#pragma unroll
        for (int off = 32; off > 0; off >>= 1)
#pragma unroll
            for (int h = 0; h < H; ++h) den[h] += __shfl_xor(den[h], off);
#pragma unroll
        for (int h = 0; h < H; ++h) {
            den[h] += __expf(eself[h] - m[h]);
            inv[h] = 1.f / (den[h] + 1e-16f);
        }
        if constexpr (H == 4) {
            float4 w = make_float4(ex[0] * inv[0], ex[1] * inv[1], ex[2] * inv[2],
                                   ex[3] * inv[3]);
            *reinterpret_cast<float4*>(&al_sh[wid][lane * 4]) = w;
        } else {
            al_sh[wid][lane] = ex[0] * inv[0];
        }
        off_sh[wid][lane] = s * M;
    } else {
#pragma unroll
        for (int h = 0; h < H; ++h) m[h] = eself[h];
        for (int base = 0; base < deg; base += 64) {
            bool valid = base + lane < deg;
            int s = valid ? csr[e0 + base + lane] : node;
            float t[H];
            load_t<H>(asb, s, valid, adn, t);
#pragma unroll
            for (int h = 0; h < H; ++h) m[h] = fmaxf(m[h], t[h]);
        }
#pragma unroll
        for (int off = 32; off > 0; off >>= 1)
#pragma unroll
            for (int h = 0; h < H; ++h) m[h] = fmaxf(m[h], __shfl_xor(m[h], off));

        float den[H];
#pragma unroll
        for (int h = 0; h < H; ++h) den[h] = 0.f;
        for (int base = 0; base < deg; base += 64) {
            bool valid = base + lane < deg;
            int s = valid ? csr[e0 + base + lane] : node;
            float t[H];
            load_t<H>(asb, s, valid, adn, t);
#pragma unroll
            for (int h = 0; h < H; ++h) den[h] += __expf(t[h] - m[h]);
        }
#pragma unroll
        for (int off = 32; off > 0; off >>= 1)
#pragma unroll
            for (int h = 0; h < H; ++h) den[h] += __shfl_xor(den[h], off);
#pragma unroll
        for (int h = 0; h < H; ++h) {
            den[h] += __expf(eself[h] - m[h]);
            inv[h] = 1.f / (den[h] + 1e-16f);
        }
    }

    // ---- accumulate ----
    int ch = lane * CPL;
    const bool active = ch < M;
    if (ch > M - CPL) ch = M - CPL;
    const int myh = ch / C;

    float mm = m[0], ii = inv[0], es = eself[0];
#pragma unroll
    for (int h = 1; h < H; ++h)
        if (myh == h) { mm = m[h]; ii = inv[h]; es = eself[h]; }

    float acc[CPL];
    const float alSelf = __expf(es - mm) * ii;
    if constexpr (CPL == 2) {
        float2 hv = __half22float2(
            *reinterpret_cast<const __half2*>(&Hh[(size_t)node * M + ch]));
        acc[0] = alSelf * hv.x;
        acc[1] = alSelf * hv.y;
    } else {
        acc[0] = alSelf * __half2float(Hh[(size_t)node * M + ch]);
    }

    auto serial = [&](int cnt) {
        for (int j0 = 0; j0 < cnt; j0 += 8) {
#pragma unroll
            for (int jj = 0; jj < 8; ++jj) {
                int j = j0 + jj;
                int wo = off_sh[wid][j];
                float al = al_sh[wid][j * H + myh];
                if constexpr (CPL == 2) {
                    __half2 h2 = *reinterpret_cast<const __half2*>(&Hh[wo + ch]);
                    float2 hv = __half22float2(h2);
                    acc[0] += al * hv.x;
                    acc[1] += al * hv.y;
                } else {
                    acc[0] += al * __half2float(Hh[wo + ch]);
                }
            }
        }
    };

    if (fast) {
        serial((deg + 7) & ~7);
    } else {
        for (int base = 0; base < deg; base += 64) {
            bool valid = base + lane < deg;
            int s = valid ? csr[e0 + base + lane] : node;
            float t[H];
            load_t<H>(asb, s, valid, adn, t);
            if constexpr (H == 4) {
                float4 w = make_float4(__expf(t[0] - m[0]) * inv[0],
                                       __expf(t[1] - m[1]) * inv[1],
                                       __expf(t[2] - m[2]) * inv[2],
                                       __expf(t[3] - m[3]) * inv[3]);
                *reinterpret_cast<float4*>(&al_sh[wid][lane * 4]) = w;
            } else {
                al_sh[wid][lane] = __expf(t[0] - m[0]) * inv[0];
            }
            off_sh[wid][lane] = s * M;
            int cl = deg - base;
            if (cl > 64) cl = 64;
            serial((cl + 7) & ~7);
        }
    }

    if (active) {
#pragma unroll
        for (int c = 0; c < CPL; ++c)
            out[(size_t)node * M + ch + c] = elu(acc[c] + bias[ch + c]);
    }
}

// ---------------- mean pool (sorted batch -> segmented reduction) ----------------
__global__ void group_bounds(const int* __restrict__ batch, int* __restrict__ gstart, int N,
                             int G) {
    int g = blockIdx.x * THREADS + threadIdx.x;
    if (g > G) return;
    int lo = 0, hi = N;
    while (lo < hi) {
        int mid = (lo + hi) >> 1;
        if (batch[mid] < g) lo = mid + 1;
        else hi = mid;
    }
    gstart[g] = lo;
}

__global__ void pool_kernel(const float* __restrict__ act, const int* __restrict__ gstart,
                            float* __restrict__ out, int G) {
    int wid = threadIdx.x >> 6;
    int lane = threadIdx.x & 63;
    int g = blockIdx.x * (THREADS / 64) + wid;
    if (g >= G) return;
    int s = gstart[g], e = gstart[g + 1];
    int c = lane & 31, half = lane >> 5;
    float acc = 0.f;
    for (int n = s + half; n < e; n += 2) acc += act[(size_t)n * 32 + c];
    acc += __shfl_xor(acc, 32);
    if (lane < 32) out[g * 32 + c] = acc / fmaxf((float)(e - s), 1.f);
}

extern "C" void kernel_launch(void* const* d_in, const int* in_sizes, int n_in, void* d_out,
                              int out_size, void* d_ws, size_t ws_size, hipStream_t stream) {
    const float* x = (const float*)d_in[0];
    const int* ei = (const int*)d_in[1];
    const int* batch = (const int*)d_in[2];
    const float* W1 = (const float*)d_in[3];
    const float* as1 = (const float*)d_in[4];
    const float* ad1 = (const float*)d_in[5];
    const float* b1 = (const float*)d_in[6];
    const float* W2 = (const float*)d_in[7];
    const float* as2 = (const float*)d_in[8];
    const float* ad2 = (const float*)d_in[9];
    const float* b2 = (const float*)d_in[10];
    const float* W3 = (const float*)d_in[11];
    const float* as3 = (const float*)d_in[12];
    const float* ad3 = (const float*)d_in[13];
    const float* b3 = (const float*)d_in[14];

    const int N = in_sizes[0] / 128;
    const int E = in_sizes[1] / 2;
    const int G = out_size / 32;
    const int* srcp = ei;
    const int* dstp = ei + E;

    char* ws = (char*)d_ws;
    float* B = (float*)ws;                        // N*128 f32
    __half* Hh = (__half*)(B + (size_t)N * 128);  // N*128 f16
    float* asb = (float*)(Hh + (size_t)N * 128);  // N*4
    float* adb = asb + (size_t)N * 4;             // N*4
    int* gstart = (int*)(adb + (size_t)N * 4);    // G+1
    int* rowptr = gstart + (G + 1);               // N+1
    int* deg = rowptr + (N + 1);                  // N
    int* cursor = deg + N;                        // N
    int* partial = cursor + N;                    // N
    int* bsum = partial + N;                      // THREADS
    int* csr = bsum + THREADS;                    // E

    const int nblk = (N + THREADS - 1) / THREADS;

    hipMemsetAsync(deg, 0, (size_t)N * 4, stream);

    hist_kernel<<<(E + THREADS - 1) / THREADS, THREADS, 0, stream>>>(dstp, deg, E);
    scan1_kernel<<<nblk, THREADS, 0, stream>>>(deg, partial, bsum, N);
    scan2_kernel<<<1, THREADS, 0, stream>>>(bsum, nblk);
    scan3_kernel<<<nblk, THREADS, 0, stream>>>(partial, bsum, rowptr, cursor, N);
    scatter_kernel<<<(E + THREADS - 1) / THREADS, THREADS, 0, stream>>>(srcp, dstp, rowptr,
                                                                        cursor, csr, E);
    group_bounds<<<(G + 1 + THREADS - 1) / THREADS, THREADS, 0, stream>>>(batch, gstart, N, G);

    const int gaBlocks = (N + 31) / 32;

    // Layer 1: x -> Hh -> B
    gemm_alpha_kernel<128, 4, 32><<<gaBlocks, THREADS, 0, stream>>>(x, W1, as1, ad1, Hh, asb,
                                                                    adb, N);
    node_aggr<128, 4, 32><<<(N + 3) / 4, THREADS, 0, stream>>>(Hh, asb, adb, rowptr, csr, b1,
                                                               B, N);
    // Layer 2: B -> Hh -> B
    gemm_alpha_kernel<128, 4, 32><<<gaBlocks, THREADS, 0, stream>>>(B, W2, as2, ad2, Hh, asb,
                                                                    adb, N);
    node_aggr<128, 4, 32><<<(N + 3) / 4, THREADS, 0, stream>>>(Hh, asb, adb, rowptr, csr, b2,
                                                               B, N);
    // Layer 3: B -> Hh(M=32) -> B
    gemm32_alpha_kernel<128><<<(N + 15) / 16, THREADS, 0, stream>>>(B, W3, as3, ad3, Hh, asb,
                                                                    adb, N);
    node_aggr<32, 1, 32><<<(N + 3) / 4, THREADS, 0, stream>>>(Hh, asb, adb, rowptr, csr, b3,
                                                              B, N);

    pool_kernel<<<(G + 3) / 4, THREADS, 0, stream>>>(B, gstart, (float*)d_out, G);
}